// Round 5
// baseline (228.233 us; speedup 1.0000x reference)
//
#include <hip/hip_runtime.h>
#include <hip/hip_bf16.h>

#define NSEG 1024
#define PIX (512 * 512)
#define NCH 21

__device__ __forceinline__ void bf16x2_to_f32(unsigned u, float& a, float& b) {
    a = __uint_as_float(u << 16);          // low bf16
    b = __uint_as_float(u & 0xffff0000u);  // high bf16
}

// Probe first 256 uint16 words. True bf16 N(0,1): exponent field ~[110,130].
// f32 data viewed as uint16: even words are random mantissa bits -> ~50% land
// in (0,64) or >=192. Any hit => buffer is f32.
__device__ int probe_is_f32(const unsigned short* p) {
    int hits = 0;
    for (int i = 0; i < 256; ++i) {
        const unsigned e = (p[i] >> 7) & 0xFFu;
        if ((e > 0u && e < 64u) || e >= 192u) ++hits;
    }
    return hits > 0 ? 1 : 0;
}

// flags: [0]=pred_is_f32, [1]=W_is_f32, [2]=L_is_f32, [3]=ids_is_i64
__global__ void detect_kernel(const unsigned short* __restrict__ pred,
                              const unsigned short* __restrict__ W,
                              const unsigned short* __restrict__ L,
                              const unsigned* __restrict__ ids,
                              int* __restrict__ flags) {
    if (threadIdx.x == 0) {
        flags[0] = probe_is_f32(pred);
        flags[1] = probe_is_f32(W);
        flags[2] = probe_is_f32(L);
        int i64 = 1;  // int64 ids in [0,1024): every odd (high) word is 0
        for (int i = 1; i < 256; i += 2)
            if (ids[i] != 0u) { i64 = 0; break; }
        flags[3] = i64;
    }
}

// K1: per-(batch, segment) sum of channel-summed pred, plus counts.
// grid (64, 4), block 512. Each thread: 8 consecutive pixels.
__global__ __launch_bounds__(512) void seg_kernel(const void* __restrict__ pred_,
                                                  const void* __restrict__ ids_,
                                                  float* __restrict__ g_sum,
                                                  float* __restrict__ g_cnt,
                                                  const int* __restrict__ flags) {
    __shared__ float s_sum[NSEG];
    __shared__ float s_cnt[NSEG];
    const int b = blockIdx.y;
    const int t = threadIdx.x;
    const int f32p = flags[0];
    const int i64 = flags[3];

    for (int i = t; i < NSEG; i += 512) { s_sum[i] = 0.f; s_cnt[i] = 0.f; }
    __syncthreads();

    // 262144 px / 64 blocks = 4096 px/block = 512 threads * 8 px
    const int base = blockIdx.x * 4096 + t * 8;
    const size_t poff = (size_t)b * NCH * PIX + base;

    float acc[8];
#pragma unroll
    for (int i = 0; i < 8; ++i) acc[i] = 0.f;

    if (f32p) {
        const float* predb = (const float*)pred_ + poff;
#pragma unroll
        for (int c = 0; c < NCH; ++c) {
            const float4 v0 = *reinterpret_cast<const float4*>(predb + (size_t)c * PIX);
            const float4 v1 = *reinterpret_cast<const float4*>(predb + (size_t)c * PIX + 4);
            acc[0] += v0.x; acc[1] += v0.y; acc[2] += v0.z; acc[3] += v0.w;
            acc[4] += v1.x; acc[5] += v1.y; acc[6] += v1.z; acc[7] += v1.w;
        }
    } else {
        const __hip_bfloat16* predb = (const __hip_bfloat16*)pred_ + poff;
#pragma unroll
        for (int c = 0; c < NCH; ++c) {
            const uint4 v = *reinterpret_cast<const uint4*>(predb + (size_t)c * PIX);
            float a, bb;
            bf16x2_to_f32(v.x, a, bb); acc[0] += a; acc[1] += bb;
            bf16x2_to_f32(v.y, a, bb); acc[2] += a; acc[3] += bb;
            bf16x2_to_f32(v.z, a, bb); acc[4] += a; acc[5] += bb;
            bf16x2_to_f32(v.w, a, bb); acc[6] += a; acc[7] += bb;
        }
    }

    int id[8];
    if (i64) {
        const int4* iv = reinterpret_cast<const int4*>((const long long*)ids_ + (size_t)b * PIX + base);
        const int4 q0 = iv[0], q1 = iv[1], q2 = iv[2], q3 = iv[3];
        id[0] = q0.x; id[1] = q0.z; id[2] = q1.x; id[3] = q1.z;
        id[4] = q2.x; id[5] = q2.z; id[6] = q3.x; id[7] = q3.z;
    } else {
        const int4* iv = reinterpret_cast<const int4*>((const int*)ids_ + (size_t)b * PIX + base);
        const int4 q0 = iv[0], q1 = iv[1];
        id[0] = q0.x; id[1] = q0.y; id[2] = q0.z; id[3] = q0.w;
        id[4] = q1.x; id[5] = q1.y; id[6] = q1.z; id[7] = q1.w;
    }

#pragma unroll
    for (int i = 0; i < 8; ++i) {
        const int s = id[i] & (NSEG - 1);
        atomicAdd(&s_sum[s], acc[i]);
        atomicAdd(&s_cnt[s], 1.f);
    }

    __syncthreads();
    float* gs = g_sum + b * NSEG;
    float* gc = g_cnt + b * NSEG;
    for (int i = t; i < NSEG; i += 512) {
        atomicAdd(&gs[i], s_sum[i]);
        atomicAdd(&gc[i], s_cnt[i]);
    }
}

// K2: quad[b] = m^T L m (blocks 0..31) and wss[b] = sum W^2 (blocks 32..47).
// grid (48, 4), block 256.
__global__ __launch_bounds__(256) void quad_kernel(const void* __restrict__ L_,
                                                   const void* __restrict__ W_,
                                                   const float* __restrict__ g_sum,
                                                   const float* __restrict__ g_cnt,
                                                   float* __restrict__ quad,
                                                   float* __restrict__ wss,
                                                   const int* __restrict__ flags) {
    const int b = blockIdx.y;
    const int t = threadIdx.x;
    const int lane = t & 63;
    const float* ss = g_sum + b * NSEG;
    const float* sc = g_cnt + b * NSEG;

    if (blockIdx.x < 32) {
        const int f32L = flags[2];
        const int wave = t >> 6;
        // lane holds m[col] for col = 2*lane + 128*j + {0,1} (pairs match row loads)
        float mreg[16];
#pragma unroll
        for (int j = 0; j < 8; ++j) {
            const int col = 2 * lane + 128 * j;
            const float c0 = sc[col], c1 = sc[col + 1];
            mreg[2 * j]     = c0 > 0.f ? ss[col] / c0 : 0.f;
            mreg[2 * j + 1] = c1 > 0.f ? ss[col + 1] / c1 : 0.f;
        }
        const int row0 = blockIdx.x * 32 + wave * 8;
        float acc = 0.f;
#pragma unroll
        for (int r = 0; r < 8; ++r) {
            const int n = row0 + r;
            const float cn = sc[n];
            const float mn = cn > 0.f ? ss[n] / cn : 0.f;  // wave-uniform broadcast
            float d = 0.f;
            if (f32L) {
                const float2* row = reinterpret_cast<const float2*>((const float*)L_ + (size_t)b * NSEG * NSEG + (size_t)n * NSEG);
#pragma unroll
                for (int j = 0; j < 8; ++j) {
                    const float2 p = row[lane + 64 * j];
                    d += p.x * mreg[2 * j] + p.y * mreg[2 * j + 1];
                }
            } else {
                const unsigned* row = reinterpret_cast<const unsigned*>((const __hip_bfloat16*)L_ + (size_t)b * NSEG * NSEG + (size_t)n * NSEG);
#pragma unroll
                for (int j = 0; j < 8; ++j) {
                    float a, bb;
                    bf16x2_to_f32(row[lane + 64 * j], a, bb);
                    d += a * mreg[2 * j] + bb * mreg[2 * j + 1];
                }
            }
            acc += mn * d;
        }
#pragma unroll
        for (int off = 32; off; off >>= 1) acc += __shfl_down(acc, off);
        if (lane == 0) atomicAdd(&quad[b], acc);
    } else {
        const int f32W = flags[1];
        const int k = blockIdx.x - 32;  // 0..15, each covers 65536 elements
        float acc = 0.f;
        if (f32W) {
            const float4* Wv = reinterpret_cast<const float4*>((const float*)W_ + (size_t)b * NSEG * NSEG + (size_t)k * 65536);
            for (int it = t; it < 16384; it += 256) {
                const float4 v = Wv[it];
                acc += v.x * v.x + v.y * v.y + v.z * v.z + v.w * v.w;
            }
        } else {
            const uint4* Wv = reinterpret_cast<const uint4*>((const __hip_bfloat16*)W_ + (size_t)b * NSEG * NSEG + (size_t)k * 65536);
            for (int it = t; it < 8192; it += 256) {
                const uint4 v = Wv[it];
                float a, bb;
                bf16x2_to_f32(v.x, a, bb); acc += a * a + bb * bb;
                bf16x2_to_f32(v.y, a, bb); acc += a * a + bb * bb;
                bf16x2_to_f32(v.z, a, bb); acc += a * a + bb * bb;
                bf16x2_to_f32(v.w, a, bb); acc += a * a + bb * bb;
            }
        }
#pragma unroll
        for (int off = 32; off; off >>= 1) acc += __shfl_down(acc, off);
        if (lane == 0) atomicAdd(&wss[b], acc);
    }
}

// K3: loss = sum_b (2/sqrt(wss)) * 21 * quad -> f32 scalar out
__global__ void final_kernel(const float* __restrict__ quad, const float* __restrict__ wss,
                             float* __restrict__ out) {
    const int t = threadIdx.x;
    float v = 0.f;
    if (t < 4) v = (2.0f / sqrtf(wss[t])) * 21.0f * quad[t];
#pragma unroll
    for (int off = 2; off; off >>= 1) v += __shfl_down(v, off);
    if (t == 0) out[0] = v;
}

extern "C" void kernel_launch(void* const* d_in, const int* in_sizes, int n_in,
                              void* d_out, int out_size, void* d_ws, size_t ws_size,
                              hipStream_t stream) {
    const void* pred = d_in[0];
    const void* W    = d_in[1];
    const void* L    = d_in[2];
    const void* ids  = d_in[3];

    float* ws    = (float*)d_ws;
    float* g_sum = ws;            // 4*1024
    float* g_cnt = ws + 4096;     // 4*1024
    float* quad  = ws + 8192;     // 4
    float* wss   = ws + 8196;     // 4
    int*   flags = (int*)(ws + 8200);  // 4

    hipMemsetAsync(d_ws, 0, 8204 * sizeof(float), stream);
    detect_kernel<<<1, 64, 0, stream>>>((const unsigned short*)pred, (const unsigned short*)W,
                                        (const unsigned short*)L, (const unsigned*)ids, flags);
    seg_kernel<<<dim3(64, 4), 512, 0, stream>>>(pred, ids, g_sum, g_cnt, flags);
    quad_kernel<<<dim3(48, 4), 256, 0, stream>>>(L, W, g_sum, g_cnt, quad, wss, flags);
    final_kernel<<<1, 64, 0, stream>>>(quad, wss, (float*)d_out);
}

// Round 6
// 199.538 us; speedup vs baseline: 1.1438x; 1.1438x over previous
//
#include <hip/hip_runtime.h>
#include <hip/hip_bf16.h>

#define NSEG 1024
#define PIX (512 * 512)
#define NCH 21

__device__ __forceinline__ void bf16x2_to_f32(unsigned u, float& a, float& b) {
    a = __uint_as_float(u << 16);          // low bf16
    b = __uint_as_float(u & 0xffff0000u);  // high bf16
}

// Lane-parallel probe of 256 uint16 words (4 per lane). True bf16 N(0,1) has
// exponent field ~[110,130]; f32 data viewed as uint16 has random low-mantissa
// words -> ~50% land in (0,64) or >=192. Any hit across the wave => f32.
__device__ __forceinline__ int lane_f32_hit(const uint2* p, int lane) {
    const uint2 v = p[lane];  // 4 uint16 words
    int hit = 0;
#pragma unroll
    for (int k = 0; k < 2; ++k) {
        const unsigned w = (k == 0) ? v.x : v.y;
        const unsigned e0 = (w >> 7) & 0xFFu;
        const unsigned e1 = (w >> 23) & 0xFFu;
        if ((e0 > 0u && e0 < 64u) || e0 >= 192u) hit = 1;
        if ((e1 > 0u && e1 < 64u) || e1 >= 192u) hit = 1;
    }
    return hit;
}

// Detect dtypes (wave 0) + zero the accumulator workspace (all 256 threads).
// flags: [0]=pred_is_f32, [1]=W_is_f32, [2]=L_is_f32, [3]=ids_is_i64
__global__ __launch_bounds__(256) void detect_kernel(const uint2* __restrict__ pred,
                                                     const uint2* __restrict__ W,
                                                     const uint2* __restrict__ L,
                                                     const uint2* __restrict__ ids,
                                                     float* __restrict__ zero_base,
                                                     int* __restrict__ flags) {
    const int t = threadIdx.x;
    for (int i = t; i < 8200; i += 256) zero_base[i] = 0.f;
    if (t < 64) {
        const int p_hit = lane_f32_hit(pred, t);
        const int w_hit = lane_f32_hit(W, t);
        const int l_hit = lane_f32_hit(L, t);
        // ids as uint2: if int64 (values < 1024), every .y (high word) is 0.
        const int odd_nz = (ids[t].y != 0u);
        const int pf = __any(p_hit), wf = __any(w_hit), lf = __any(l_hit);
        const int i64 = !__any(odd_nz);
        if (t == 0) { flags[0] = pf; flags[1] = wf; flags[2] = lf; flags[3] = i64; }
    }
}

// K1: per-(batch, segment) sum of channel-summed pred, plus counts.
// grid (64, 4), block 512. Each thread: 8 consecutive pixels.
__global__ __launch_bounds__(512) void seg_kernel(const void* __restrict__ pred_,
                                                  const void* __restrict__ ids_,
                                                  float* __restrict__ g_sum,
                                                  float* __restrict__ g_cnt,
                                                  const int* __restrict__ flags) {
    __shared__ float s_sum[NSEG];
    __shared__ float s_cnt[NSEG];
    const int b = blockIdx.y;
    const int t = threadIdx.x;
    const int f32p = flags[0];
    const int i64 = flags[3];

    for (int i = t; i < NSEG; i += 512) { s_sum[i] = 0.f; s_cnt[i] = 0.f; }
    __syncthreads();

    // 262144 px / 64 blocks = 4096 px/block = 512 threads * 8 px
    const int base = blockIdx.x * 4096 + t * 8;
    const size_t poff = (size_t)b * NCH * PIX + base;

    float acc[8];
#pragma unroll
    for (int i = 0; i < 8; ++i) acc[i] = 0.f;

    if (f32p) {
        const float* predb = (const float*)pred_ + poff;
#pragma unroll
        for (int c = 0; c < NCH; ++c) {
            const float4 v0 = *reinterpret_cast<const float4*>(predb + (size_t)c * PIX);
            const float4 v1 = *reinterpret_cast<const float4*>(predb + (size_t)c * PIX + 4);
            acc[0] += v0.x; acc[1] += v0.y; acc[2] += v0.z; acc[3] += v0.w;
            acc[4] += v1.x; acc[5] += v1.y; acc[6] += v1.z; acc[7] += v1.w;
        }
    } else {
        const __hip_bfloat16* predb = (const __hip_bfloat16*)pred_ + poff;
#pragma unroll
        for (int c = 0; c < NCH; ++c) {
            const uint4 v = *reinterpret_cast<const uint4*>(predb + (size_t)c * PIX);
            float a, bb;
            bf16x2_to_f32(v.x, a, bb); acc[0] += a; acc[1] += bb;
            bf16x2_to_f32(v.y, a, bb); acc[2] += a; acc[3] += bb;
            bf16x2_to_f32(v.z, a, bb); acc[4] += a; acc[5] += bb;
            bf16x2_to_f32(v.w, a, bb); acc[6] += a; acc[7] += bb;
        }
    }

    int id[8];
    if (i64) {
        const int4* iv = reinterpret_cast<const int4*>((const long long*)ids_ + (size_t)b * PIX + base);
        const int4 q0 = iv[0], q1 = iv[1], q2 = iv[2], q3 = iv[3];
        id[0] = q0.x; id[1] = q0.z; id[2] = q1.x; id[3] = q1.z;
        id[4] = q2.x; id[5] = q2.z; id[6] = q3.x; id[7] = q3.z;
    } else {
        const int4* iv = reinterpret_cast<const int4*>((const int*)ids_ + (size_t)b * PIX + base);
        const int4 q0 = iv[0], q1 = iv[1];
        id[0] = q0.x; id[1] = q0.y; id[2] = q0.z; id[3] = q0.w;
        id[4] = q1.x; id[5] = q1.y; id[6] = q1.z; id[7] = q1.w;
    }

#pragma unroll
    for (int i = 0; i < 8; ++i) {
        const int s = id[i] & (NSEG - 1);
        atomicAdd(&s_sum[s], acc[i]);
        atomicAdd(&s_cnt[s], 1.f);
    }

    __syncthreads();
    float* gs = g_sum + b * NSEG;
    float* gc = g_cnt + b * NSEG;
    for (int i = t; i < NSEG; i += 512) {
        atomicAdd(&gs[i], s_sum[i]);
        atomicAdd(&gc[i], s_cnt[i]);
    }
}

// K2: quad[b] = m^T L m (blocks 0..31) and wss[b] = sum W^2 (blocks 32..47).
// grid (48, 4), block 256.
__global__ __launch_bounds__(256) void quad_kernel(const void* __restrict__ L_,
                                                   const void* __restrict__ W_,
                                                   const float* __restrict__ g_sum,
                                                   const float* __restrict__ g_cnt,
                                                   float* __restrict__ quad,
                                                   float* __restrict__ wss,
                                                   const int* __restrict__ flags) {
    const int b = blockIdx.y;
    const int t = threadIdx.x;
    const int lane = t & 63;
    const float* ss = g_sum + b * NSEG;
    const float* sc = g_cnt + b * NSEG;

    if (blockIdx.x < 32) {
        const int f32L = flags[2];
        const int wave = t >> 6;
        // lane holds m[col] for col = 2*lane + 128*j + {0,1} (pairs match row loads)
        float mreg[16];
#pragma unroll
        for (int j = 0; j < 8; ++j) {
            const int col = 2 * lane + 128 * j;
            const float c0 = sc[col], c1 = sc[col + 1];
            mreg[2 * j]     = c0 > 0.f ? ss[col] / c0 : 0.f;
            mreg[2 * j + 1] = c1 > 0.f ? ss[col + 1] / c1 : 0.f;
        }
        const int row0 = blockIdx.x * 32 + wave * 8;
        float acc = 0.f;
#pragma unroll
        for (int r = 0; r < 8; ++r) {
            const int n = row0 + r;
            const float cn = sc[n];
            const float mn = cn > 0.f ? ss[n] / cn : 0.f;  // wave-uniform broadcast
            float d = 0.f;
            if (f32L) {
                const float2* row = reinterpret_cast<const float2*>((const float*)L_ + (size_t)b * NSEG * NSEG + (size_t)n * NSEG);
#pragma unroll
                for (int j = 0; j < 8; ++j) {
                    const float2 p = row[lane + 64 * j];
                    d += p.x * mreg[2 * j] + p.y * mreg[2 * j + 1];
                }
            } else {
                const unsigned* row = reinterpret_cast<const unsigned*>((const __hip_bfloat16*)L_ + (size_t)b * NSEG * NSEG + (size_t)n * NSEG);
#pragma unroll
                for (int j = 0; j < 8; ++j) {
                    float a, bb;
                    bf16x2_to_f32(row[lane + 64 * j], a, bb);
                    d += a * mreg[2 * j] + bb * mreg[2 * j + 1];
                }
            }
            acc += mn * d;
        }
#pragma unroll
        for (int off = 32; off; off >>= 1) acc += __shfl_down(acc, off);
        if (lane == 0) atomicAdd(&quad[b], acc);
    } else {
        const int f32W = flags[1];
        const int k = blockIdx.x - 32;  // 0..15, each covers 65536 elements
        float acc = 0.f;
        if (f32W) {
            const float4* Wv = reinterpret_cast<const float4*>((const float*)W_ + (size_t)b * NSEG * NSEG + (size_t)k * 65536);
            for (int it = t; it < 16384; it += 256) {
                const float4 v = Wv[it];
                acc += v.x * v.x + v.y * v.y + v.z * v.z + v.w * v.w;
            }
        } else {
            const uint4* Wv = reinterpret_cast<const uint4*>((const __hip_bfloat16*)W_ + (size_t)b * NSEG * NSEG + (size_t)k * 65536);
            for (int it = t; it < 8192; it += 256) {
                const uint4 v = Wv[it];
                float a, bb;
                bf16x2_to_f32(v.x, a, bb); acc += a * a + bb * bb;
                bf16x2_to_f32(v.y, a, bb); acc += a * a + bb * bb;
                bf16x2_to_f32(v.z, a, bb); acc += a * a + bb * bb;
                bf16x2_to_f32(v.w, a, bb); acc += a * a + bb * bb;
            }
        }
#pragma unroll
        for (int off = 32; off; off >>= 1) acc += __shfl_down(acc, off);
        if (lane == 0) atomicAdd(&wss[b], acc);
    }
}

// K3: loss = sum_b (2/sqrt(wss)) * 21 * quad -> f32 scalar out
__global__ void final_kernel(const float* __restrict__ quad, const float* __restrict__ wss,
                             float* __restrict__ out) {
    const int t = threadIdx.x;
    float v = 0.f;
    if (t < 4) v = (2.0f / sqrtf(wss[t])) * 21.0f * quad[t];
#pragma unroll
    for (int off = 2; off; off >>= 1) v += __shfl_down(v, off);
    if (t == 0) out[0] = v;
}

extern "C" void kernel_launch(void* const* d_in, const int* in_sizes, int n_in,
                              void* d_out, int out_size, void* d_ws, size_t ws_size,
                              hipStream_t stream) {
    const void* pred = d_in[0];
    const void* W    = d_in[1];
    const void* L    = d_in[2];
    const void* ids  = d_in[3];

    float* ws    = (float*)d_ws;
    float* g_sum = ws;            // 4*1024
    float* g_cnt = ws + 4096;     // 4*1024
    float* quad  = ws + 8192;     // 4
    float* wss   = ws + 8196;     // 4
    int*   flags = (int*)(ws + 8200);  // 4 (written unconditionally, not pre-zeroed)

    detect_kernel<<<1, 256, 0, stream>>>((const uint2*)pred, (const uint2*)W,
                                         (const uint2*)L, (const uint2*)ids, ws, flags);
    seg_kernel<<<dim3(64, 4), 512, 0, stream>>>(pred, ids, g_sum, g_cnt, flags);
    quad_kernel<<<dim3(48, 4), 256, 0, stream>>>(L, W, g_sum, g_cnt, quad, wss, flags);
    final_kernel<<<1, 64, 0, stream>>>(quad, wss, (float*)d_out);
}